// Round 5
// baseline (189.277 us; speedup 1.0000x reference)
//
#include <hip/hip_runtime.h>
#include <hip/hip_bf16.h>
#include <hip/hip_fp16.h>

// CausalSelfAttention  B=4, S=2048, D=1024 (single wide head), fp32 in/out.
// R5: generalized 8-phase counted-vmcnt NT-GEMM template (proven R3/R4 core),
// instantiated per-leg for grid-packing:
//   QKV:    BM256 BN192, 6 waves (2x3, wave tile 128x64), 512 blocks = 2 rounds
//   scores: BM256 BN128, 4 waves (2x2, wave tile 128x64), 288 live blocks
//   PV:     BM64  BN256, 4 waves (1x4), 80KB LDS -> 2 blocks/CU, longest-first,
//           K rounded to even tiles (exact: P masked region is zeros)

using bf16 = __hip_bfloat16;
typedef __bf16 bf16x8 __attribute__((ext_vector_type(8)));
typedef float f32x4 __attribute__((ext_vector_type(4)));

__device__ __forceinline__ void load_lds_16B(const void* g, void* l) {
  __builtin_amdgcn_global_load_lds(
      (const __attribute__((address_space(1))) unsigned int*)g,
      (__attribute__((address_space(3))) unsigned int*)l, 16, 0, 0);
}

template <int N>
__device__ __forceinline__ void waitcnt_vm() {
  if constexpr (N == 10) asm volatile("s_waitcnt vmcnt(10)" ::: "memory");
  else if constexpr (N == 9) asm volatile("s_waitcnt vmcnt(9)" ::: "memory");
  else if constexpr (N == 8) asm volatile("s_waitcnt vmcnt(8)" ::: "memory");
  else if constexpr (N == 6) asm volatile("s_waitcnt vmcnt(6)" ::: "memory");
  else if constexpr (N == 5) asm volatile("s_waitcnt vmcnt(5)" ::: "memory");
  else asm volatile("s_waitcnt vmcnt(0)" ::: "memory");
}

// XOR bits[6:4] by bits[9:7] (disjoint -> involution). Verified 0 bank
// conflicts (R2-R4 rocprof).
__device__ __forceinline__ int swz(int o) { return o ^ (((o >> 7) & 7) << 4); }

// ---------------------------------------------------------------------------
// NT GEMM: C[M,N] = A[M,K]*B[N,K]^T, strides lda/ldb/ldc (elements).
// WM x WN waves, wave tile (BM/WM) x (BN/WN). BK=64 as two kc=32 chunks.
// 8 phases / 2 K-tiles; staging 1 half-chunk per phase on threads < STHR;
// vmcnt(ACALLS+2*BCALLS) at phases 4 & 8. OUT: 0=fp32, 1=bf16, 2=fp16.
// ---------------------------------------------------------------------------
template <int BM, int BN, int WM, int WN, int STHR, int OCC, int OUT,
          bool CSKIP, bool KLIM>
__global__ __launch_bounds__(WM* WN * 64, OCC) void gemmT(
    const bf16* __restrict__ A, const bf16* __restrict__ Bm, void* __restrict__ Cv,
    int K, int lda, int ldb, int ldc, long sAz, long sBz, long sCzBytes) {
  constexpr int MR = BM / WM / 16, NR = BN / WN / 16, MH2 = MR / 2;
  constexpr int AKC = BM * 64;   // bytes per A kc-chunk [BM][32]bf16
  constexpr int BKC = BN * 64;   // bytes per B kc-chunk
  constexpr int DBSTR = 2 * (AKC + BKC);
  constexpr int CHUNK = STHR * 16;
  constexpr int ACALLS = AKC / CHUNK;
  constexpr int BCALLS = BKC / CHUNK;
  constexpr int VM_LEAVE = ACALLS + 2 * BCALLS;

  const int tn = blockIdx.x, z = blockIdx.z;
  const int tm = KLIM ? (gridDim.y - 1 - blockIdx.y) : blockIdx.y;  // longest-first
  if (CSKIP && (long)tn * BN >= (long)tm * BM + BM) return;
  A += (long)z * sAz;
  Bm += (long)z * sBz;
  char* C = (char*)Cv + (long)z * sCzBytes;

  int kEnd = K;
  if (KLIM) kEnd = min(tm * BM + BM, K);
  int nt = kEnd >> 6;
  if (KLIM) nt = (nt + 1) & ~1;  // round up to even; extra K reads zeros of P
  const int NI = nt >> 1;

  __shared__ __align__(128) char sm[2 * DBSTR];
  const int tid = threadIdx.x, lane = tid & 63, wv = tid >> 6;
  const int wr = wv / WN, wc = wv % WN;
  const int ldsw = (tid >> 6) * 1024;

  // staging: linear LDS dest, pre-swizzled global source (both-sides rule)
  const int ts = (tid < STHR) ? tid : 0;
  const char* srcA[ACALLS];
  const char* srcB[BCALLS];
#pragma unroll
  for (int c = 0; c < ACALLS; c++) {
    int os = swz(c * CHUNK + ts * 16);
    srcA[c] = (const char*)(A + ((long)tm * BM + (os >> 6)) * lda) + (os & 63);
  }
#pragma unroll
  for (int c = 0; c < BCALLS; c++) {
    int os = swz(c * CHUNK + ts * 16);
    srcB[c] = (const char*)(Bm + ((long)tn * BN + (os >> 6)) * ldb) + (os & 63);
  }
  auto stageA = [&](int t, int kc) {
    if (tid < STHR) {
#pragma unroll
      for (int c = 0; c < ACALLS; c++)
        load_lds_16B(srcA[c] + (long)t * 128 + kc * 64,
                     sm + (t & 1) * DBSTR + kc * AKC + c * CHUNK + ldsw);
    }
  };
  auto stageB = [&](int t, int kc) {
    if (tid < STHR) {
#pragma unroll
      for (int c = 0; c < BCALLS; c++)
        load_lds_16B(srcB[c] + (long)t * 128 + kc * 64,
                     sm + (t & 1) * DBSTR + 2 * AKC + kc * BKC + c * CHUNK + ldsw);
    }
  };

  int aoff[MR], boff[NR];
#pragma unroll
  for (int m = 0; m < MR; m++)
    aoff[m] = swz((wr * (BM / WM) + m * 16 + (lane & 15)) * 64 + (lane >> 4) * 16);
#pragma unroll
  for (int n = 0; n < NR; n++)
    boff[n] = 2 * AKC + swz((wc * (BN / WN) + n * 16 + (lane & 15)) * 64 + (lane >> 4) * 16);

  f32x4 acc[MR][NR] = {};
  bf16x8 bfr[2][NR];
  bf16x8 afrA[MH2], afrB[MH2];

#define LDB(DBUF, KC)                                                          \
  _Pragma("unroll") for (int n = 0; n < NR; n++)                               \
      bfr[KC][n] = *(const bf16x8*)(sm + (DBUF)*DBSTR + (KC)*BKC + boff[n]);
#define LDA(DBUF, KC, MH, DST)                                                 \
  _Pragma("unroll") for (int m = 0; m < MH2; m++)                              \
      DST[m] = *(const bf16x8*)(sm + (DBUF)*DBSTR + (KC)*AKC + aoff[(MH)*MH2 + m]);
#define MFMAS(KC, MH, AFR)                                                     \
  __builtin_amdgcn_s_setprio(1);                                               \
  _Pragma("unroll") for (int m = 0; m < MH2; m++)                              \
      _Pragma("unroll") for (int n = 0; n < NR; n++)                           \
          acc[(MH)*MH2 + m][n] = __builtin_amdgcn_mfma_f32_16x16x32_bf16(      \
              AFR[m], bfr[KC][n], acc[(MH)*MH2 + m][n], 0, 0, 0);              \
  __builtin_amdgcn_s_setprio(0);
#define BAR1()                                                                 \
  __builtin_amdgcn_s_barrier();                                                \
  asm volatile("s_waitcnt lgkmcnt(0)" ::: "memory");                           \
  __builtin_amdgcn_sched_barrier(0);
#define BAR2() __builtin_amdgcn_s_barrier();

  // prologue: tile0 fully + tile1 minus Ak1 (completed by first P1)
  stageB(0, 0); stageA(0, 0); stageB(0, 1); stageA(0, 1);
  stageB(1, 0); stageA(1, 0); stageB(1, 1);
  waitcnt_vm<VM_LEAVE>();
  __builtin_amdgcn_s_barrier();

  for (int i = 0; i < NI - 1; i++) {
    const int ta = 2 * i, tb = 2 * i + 1;
    LDB(0, 0); LDA(0, 0, 0, afrA); stageA(tb, 1);     BAR1(); MFMAS(0, 0, afrA); BAR2();
    LDA(0, 0, 1, afrB);            stageB(ta + 2, 0); BAR1(); MFMAS(0, 1, afrB); BAR2();
    LDB(0, 1); LDA(0, 1, 0, afrA); stageA(ta + 2, 0); BAR1(); MFMAS(1, 0, afrA); BAR2();
    LDA(0, 1, 1, afrB);            stageB(ta + 2, 1);
    waitcnt_vm<VM_LEAVE>();                           BAR1(); MFMAS(1, 1, afrB); BAR2();
    LDB(1, 0); LDA(1, 0, 0, afrA); stageA(ta + 2, 1); BAR1(); MFMAS(0, 0, afrA); BAR2();
    LDA(1, 0, 1, afrB);            stageB(tb + 2, 0); BAR1(); MFMAS(0, 1, afrB); BAR2();
    LDB(1, 1); LDA(1, 1, 0, afrA); stageA(tb + 2, 0); BAR1(); MFMAS(1, 0, afrA); BAR2();
    LDA(1, 1, 1, afrB);            stageB(tb + 2, 1);
    waitcnt_vm<VM_LEAVE>();                           BAR1(); MFMAS(1, 1, afrB); BAR2();
  }
  {  // tail: tiles nt-2, nt-1; no further staging
    const int tb = nt - 1;
    LDB(0, 0); LDA(0, 0, 0, afrA); stageA(tb, 1); BAR1(); MFMAS(0, 0, afrA); BAR2();
    LDA(0, 0, 1, afrB);                           BAR1(); MFMAS(0, 1, afrB); BAR2();
    LDB(0, 1); LDA(0, 1, 0, afrA);                BAR1(); MFMAS(1, 0, afrA); BAR2();
    LDA(0, 1, 1, afrB); waitcnt_vm<0>();          BAR1(); MFMAS(1, 1, afrB); BAR2();
    LDB(1, 0); LDA(1, 0, 0, afrA);                BAR1(); MFMAS(0, 0, afrA); BAR2();
    LDA(1, 0, 1, afrB);                           BAR1(); MFMAS(0, 1, afrB); BAR2();
    LDB(1, 1); LDA(1, 1, 0, afrA);                BAR1(); MFMAS(1, 0, afrA); BAR2();
    LDA(1, 1, 1, afrB);                           BAR1(); MFMAS(1, 1, afrB); BAR2();
  }
#undef LDB
#undef LDA
#undef MFMAS
#undef BAR1
#undef BAR2

  // epilogue: D row = (lane>>4)*4 + j, col = lane&15 (m89-verified)
  const int cr0 = tm * BM + wr * (BM / WM) + (lane >> 4) * 4;
  const int cc0 = tn * BN + wc * (BN / WN) + (lane & 15);
#pragma unroll
  for (int m = 0; m < MR; m++)
#pragma unroll
    for (int n = 0; n < NR; n++)
#pragma unroll
      for (int j = 0; j < 4; j++) {
        long row = cr0 + m * 16 + j;
        long col = cc0 + n * 16;
        if (OUT == 1)
          ((bf16*)C)[row * (long)ldc + col] = __float2bfloat16(acc[m][n][j]);
        else if (OUT == 2)
          ((__half*)C)[row * (long)ldc + col] = __float2half(acc[m][n][j]);
        else
          ((float*)C)[row * (long)ldc + col] = acc[m][n][j];
      }
}

// ---------------------------------------------------------------------------
// fused fp32 -> bf16 convert for x, Wq, Wk, Wv (one dispatch)
// ---------------------------------------------------------------------------
__global__ __launch_bounds__(256) void cvt_all(const float* __restrict__ x,
                                               const float* __restrict__ wq,
                                               const float* __restrict__ wk,
                                               const float* __restrict__ wv,
                                               bf16* __restrict__ xb,
                                               bf16* __restrict__ wb) {
  const int b = blockIdx.x;
  const float* src;
  bf16* dst;
  int i;
  if (b < 8192) { src = x; dst = xb; i = b * 256 + threadIdx.x; }
  else if (b < 9216) { src = wq; dst = wb; i = (b - 8192) * 256 + threadIdx.x; }
  else if (b < 10240) { src = wk; dst = wb + 1048576; i = (b - 9216) * 256 + threadIdx.x; }
  else { src = wv; dst = wb + 2097152; i = (b - 10240) * 256 + threadIdx.x; }
  float4 f = ((const float4*)src)[i];
  union { bf16 h[4]; uint2 u; } o;
  o.h[0] = __float2bfloat16(f.x);
  o.h[1] = __float2bfloat16(f.y);
  o.h[2] = __float2bfloat16(f.z);
  o.h[3] = __float2bfloat16(f.w);
  ((uint2*)dst)[i] = o.u;
}

// ---------------------------------------------------------------------------
// causal row softmax on fp16 scores: P = softmax_j<=i(S/32), 0 for j>i (bf16)
// ---------------------------------------------------------------------------
typedef short short4v __attribute__((ext_vector_type(4)));

__global__ __launch_bounds__(256) void softmax_causal(const __half* __restrict__ Sc,
                                                      bf16* __restrict__ P) {
  const int i = blockIdx.x, b = blockIdx.y;
  const long base = ((long)b * 2048 + i) * 2048;
  const __half* row = Sc + base;
  bf16* prow = P + base;
  const int tid = threadIdx.x, lane = tid & 63, wv = tid >> 6;
  const int len = i + 1;

  float v[8];
  float m = -3.3e38f;
  {
    const int j0 = tid * 8;
    union { short4v s[2]; __half h[8]; } u;
    u.s[0] = *(const short4v*)(row + j0);
    u.s[1] = *(const short4v*)(row + j0 + 4);
#pragma unroll
    for (int e = 0; e < 8; e++) {
      float t = __half2float(u.h[e]);
      v[e] = (j0 + e < len) ? t : -3.3e38f;
      m = fmaxf(m, v[e]);
    }
  }
  for (int o = 32; o; o >>= 1) m = fmaxf(m, __shfl_xor(m, o));
  __shared__ float redm[4], reds[4];
  if (lane == 0) redm[wv] = m;
  __syncthreads();
  m = fmaxf(fmaxf(redm[0], redm[1]), fmaxf(redm[2], redm[3]));

  const float scale = 0.03125f;  // 1/sqrt(1024)
  float e8[8];
  float s = 0.f;
  {
    const int j0 = tid * 8;
#pragma unroll
    for (int e = 0; e < 8; e++) {
      float t = (j0 + e < len) ? __expf((v[e] - m) * scale) : 0.f;
      e8[e] = t;
      s += t;
    }
  }
  for (int o = 32; o; o >>= 1) s += __shfl_xor(s, o);
  if (lane == 0) reds[wv] = s;
  __syncthreads();
  s = reds[0] + reds[1] + reds[2] + reds[3];
  const float inv = 1.0f / s;
  {
    const int j0 = tid * 8;
    union { bf16 h[8]; uint4 u4; } o;
#pragma unroll
    for (int e = 0; e < 8; e++) o.h[e] = __float2bfloat16(e8[e] * inv);
    *(uint4*)(prow + j0) = o.u4;
  }
}

// ---------------------------------------------------------------------------
// V (cols 2048.. of Cqkv, row stride 3072) -> Vt[b,d,s] (bf16)
// ---------------------------------------------------------------------------
__global__ __launch_bounds__(256) void transposeV(const bf16* __restrict__ V,
                                                  bf16* __restrict__ Vt) {
  __shared__ bf16 t[32][33];
  const int b = blockIdx.z;
  const int s0 = blockIdx.x << 5;
  const int d0 = blockIdx.y << 5;
  const bf16* Vb = V + (long)b * 2048 * 3072;
  bf16* Vtb = Vt + (long)b * 1024 * 2048;
  const int lx = threadIdx.x & 31, ly = threadIdx.x >> 5;
#pragma unroll
  for (int r = 0; r < 32; r += 8)
    t[r + ly][lx] = Vb[(long)(s0 + r + ly) * 3072 + d0 + lx];
  __syncthreads();
#pragma unroll
  for (int r = 0; r < 32; r += 8)
    Vtb[(long)(d0 + r + ly) * 2048 + s0 + lx] = t[lx][r + ly];
}

// ---------------------------------------------------------------------------
// Workspace (160 MB):
//   [0,48M)    Cqkv bf16 [8192][3072]  (Q|K|V interleaved, ld=3072)
//   [48,64M)   Vt bf16 [4][1024][2048]
//   [64,96M)   P bf16 [4][2048][2048]
//   [96,128M)  Sc fp16 [4][2048][2048] -- aliases xb@96M + Wb@112M (dead
//                                         after QKV GEMM; Sc written later)
// ---------------------------------------------------------------------------
extern "C" void kernel_launch(void* const* d_in, const int* in_sizes, int n_in,
                              void* d_out, int out_size, void* d_ws, size_t ws_size,
                              hipStream_t stream) {
  const float* x = (const float*)d_in[0];
  const float* Wq = (const float*)d_in[1];
  const float* Wk = (const float*)d_in[2];
  const float* Wv = (const float*)d_in[3];

  const long MBy = 1 << 20;
  char* ws = (char*)d_ws;
  bf16* Cqkv = (bf16*)(ws);
  bf16* Vt = (bf16*)(ws + 48 * MBy);
  bf16* P = (bf16*)(ws + 64 * MBy);
  __half* Sc = (__half*)(ws + 96 * MBy);
  bf16* xb = (bf16*)(ws + 96 * MBy);
  bf16* Wb = (bf16*)(ws + 112 * MBy);

  // 1) convert inputs to bf16 (single dispatch)
  cvt_all<<<11264, 256, 0, stream>>>(x, Wq, Wk, Wv, xb, Wb);

  // 2) fused QKV: [8192,3072] = xb * Wb^T. BM=256,BN=192, 6 waves (2x3),
  //    512 blocks = 2 exact rounds, wave tile 128x64.
  gemmT<256, 192, 2, 3, 256, 1, 1, false, false><<<dim3(16, 32), 384, 0, stream>>>(
      xb, Wb, Cqkv, 1024, 1024, 1024, 3072, 0L, 0L, 0L);

  // 3) V transpose (V = Cqkv cols [2048,3072), row stride 3072)
  transposeV<<<dim3(64, 32, 4), 256, 0, stream>>>(Cqkv + 2048, Vt);

  // 4) scores: per batch S = Q*K^T (fp16 out), skip masked tiles.
  //    BM=256,BN=128, 4 waves (2x2), 288 live blocks, wave tile 128x64.
  gemmT<256, 128, 2, 2, 256, 1, 2, true, false><<<dim3(16, 8, 4), 256, 0, stream>>>(
      Cqkv, Cqkv + 1024, Sc, 1024, 3072, 3072, 2048,
      2048L * 3072, 2048L * 3072, 2048L * 2048 * 2);

  // 5) causal softmax (applies 1/32 scale), P bf16 with zeros above diagonal
  softmax_causal<<<dim3(2048, 4), 256, 0, stream>>>(Sc, P);

  // 6) out = P * Vt^T fp32. BM=64, 4 waves (1x4), 80KB LDS -> 2 blocks/CU,
  //    longest-K-first (reversed tm), nt rounded even (P zeros make it exact).
  gemmT<64, 256, 1, 4, 256, 2, 0, false, true><<<dim3(4, 32, 4), 256, 0, stream>>>(
      P, Vt, d_out, 2048, 2048, 2048, 1024,
      2048L * 2048, 1024L * 2048, 2048L * 1024 * 4);
}

// Round 6
// 171.770 us; speedup vs baseline: 1.1019x; 1.1019x over previous
//
#include <hip/hip_runtime.h>
#include <hip/hip_bf16.h>
#include <hip/hip_fp16.h>

// CausalSelfAttention  B=4, S=2048, D=1024 (single wide head), fp32 in/out.
// R6: QKV restored to R4's best config (BM128xBN256, 8 waves, 64us).
//     scores: BM=BN=128, 4 waves, 64KB LDS -> 2 blocks/CU, 544 live blocks.
//     PV: BM=BN=128, paired row-tiles (y, 15-y) -> constant K=2176 per block,
//         perfectly balanced single round of 256 blocks @ 2/CU.

using bf16 = __hip_bfloat16;
typedef __bf16 bf16x8 __attribute__((ext_vector_type(8)));
typedef float f32x4 __attribute__((ext_vector_type(4)));

__device__ __forceinline__ void load_lds_16B(const void* g, void* l) {
  __builtin_amdgcn_global_load_lds(
      (const __attribute__((address_space(1))) unsigned int*)g,
      (__attribute__((address_space(3))) unsigned int*)l, 16, 0, 0);
}

template <int N>
__device__ __forceinline__ void waitcnt_vm() {
  if constexpr (N == 8) asm volatile("s_waitcnt vmcnt(8)" ::: "memory");
  else if constexpr (N == 6) asm volatile("s_waitcnt vmcnt(6)" ::: "memory");
  else if constexpr (N == 5) asm volatile("s_waitcnt vmcnt(5)" ::: "memory");
  else asm volatile("s_waitcnt vmcnt(0)" ::: "memory");
}

// XOR bits[6:4] by bits[9:7] (disjoint -> involution). Verified 0 bank
// conflicts (R2-R5 rocprof).
__device__ __forceinline__ int swz(int o) { return o ^ (((o >> 7) & 7) << 4); }

// ---------------------------------------------------------------------------
// NT GEMM: C[M,N] = A[M,K]*B[N,K]^T, strides lda/ldb/ldc (elements).
// WM x WN waves, wave tile (BM/WM) x (BN/WN). BK=64 as two kc=32 chunks.
// 8 phases / 2 K-tiles; 1 staging half-chunk per phase; counted vmcnt at
// phases 4 & 8. OUT: 0=fp32, 1=bf16, 2=fp16.
// NPASS=2: block serially processes row-tiles blockIdx.y and
// 2*gridDim.y-1-blockIdx.y (KLIM pairing -> constant total K per block).
// ---------------------------------------------------------------------------
template <int BM, int BN, int WM, int WN, int STHR, int OCC, int OUT,
          bool CSKIP, bool KLIM, int NPASS>
__global__ __launch_bounds__(WM* WN * 64, OCC) void gemmT(
    const bf16* __restrict__ A, const bf16* __restrict__ Bm, void* __restrict__ Cv,
    int K, int lda, int ldb, int ldc, long sAz, long sBz, long sCzBytes) {
  constexpr int MR = BM / WM / 16, NR = BN / WN / 16, MH2 = MR / 2;
  constexpr int AKC = BM * 64;   // bytes per A kc-chunk [BM][32]bf16
  constexpr int BKC = BN * 64;   // bytes per B kc-chunk
  constexpr int DBSTR = 2 * (AKC + BKC);
  constexpr int CHUNK = STHR * 16;
  constexpr int ACALLS = AKC / CHUNK;
  constexpr int BCALLS = BKC / CHUNK;
  constexpr int VM_LEAVE = ACALLS + 2 * BCALLS;

  const int tn = blockIdx.x, z = blockIdx.z;
  if (CSKIP && (long)tn * BN >= (long)blockIdx.y * BM + BM) return;
  A += (long)z * sAz;
  Bm += (long)z * sBz;
  char* C = (char*)Cv + (long)z * sCzBytes;

  __shared__ __align__(128) char sm[2 * DBSTR];
  const int tid = threadIdx.x, lane = tid & 63, wv = tid >> 6;
  const int wr = wv / WN, wc = wv % WN;
  const int ldsw = wv * 1024;
  const int ts = (tid < STHR) ? tid : 0;

  int aoff[MR], boff[NR];
#pragma unroll
  for (int m = 0; m < MR; m++)
    aoff[m] = swz((wr * (BM / WM) + m * 16 + (lane & 15)) * 64 + (lane >> 4) * 16);
#pragma unroll
  for (int n = 0; n < NR; n++)
    boff[n] = 2 * AKC + swz((wc * (BN / WN) + n * 16 + (lane & 15)) * 64 + (lane >> 4) * 16);

  const char* srcB[BCALLS];
#pragma unroll
  for (int c = 0; c < BCALLS; c++) {
    int os = swz(c * CHUNK + ts * 16);
    srcB[c] = (const char*)(Bm + ((long)tn * BN + (os >> 6)) * ldb) + (os & 63);
  }

  for (int pass = 0; pass < NPASS; ++pass) {
    const int tm = (NPASS == 2)
                       ? (pass == 0 ? blockIdx.y : 2 * (int)gridDim.y - 1 - (int)blockIdx.y)
                       : (int)blockIdx.y;

    int kEnd = K;
    if (KLIM) kEnd = min(tm * BM + BM, K);  // causal PV: P[q,k]==0 for k>q
    int nt = kEnd >> 6;
    if (KLIM) nt = (nt + 1) & ~1;  // even tiles; extra K reads zeros of P
    const int NI = nt >> 1;

    const char* srcA[ACALLS];
#pragma unroll
    for (int c = 0; c < ACALLS; c++) {
      int os = swz(c * CHUNK + ts * 16);
      srcA[c] = (const char*)(A + ((long)tm * BM + (os >> 6)) * lda) + (os & 63);
    }
    auto stageA = [&](int t, int kc) {
      if (tid < STHR) {
#pragma unroll
        for (int c = 0; c < ACALLS; c++)
          load_lds_16B(srcA[c] + (long)t * 128 + kc * 64,
                       sm + (t & 1) * DBSTR + kc * AKC + c * CHUNK + ldsw);
      }
    };
    auto stageB = [&](int t, int kc) {
      if (tid < STHR) {
#pragma unroll
        for (int c = 0; c < BCALLS; c++)
          load_lds_16B(srcB[c] + (long)t * 128 + kc * 64,
                       sm + (t & 1) * DBSTR + 2 * AKC + kc * BKC + c * CHUNK + ldsw);
      }
    };

    f32x4 acc[MR][NR] = {};
    bf16x8 bfr[2][NR];
    bf16x8 afrA[MH2], afrB[MH2];

#define LDB(DBUF, KC)                                                          \
  _Pragma("unroll") for (int n = 0; n < NR; n++)                               \
      bfr[KC][n] = *(const bf16x8*)(sm + (DBUF)*DBSTR + (KC)*BKC + boff[n]);
#define LDA(DBUF, KC, MH, DST)                                                 \
  _Pragma("unroll") for (int m = 0; m < MH2; m++)                              \
      DST[m] = *(const bf16x8*)(sm + (DBUF)*DBSTR + (KC)*AKC + aoff[(MH)*MH2 + m]);
#define MFMAS(KC, MH, AFR)                                                     \
  __builtin_amdgcn_s_setprio(1);                                               \
  _Pragma("unroll") for (int m = 0; m < MH2; m++)                              \
      _Pragma("unroll") for (int n = 0; n < NR; n++)                           \
          acc[(MH)*MH2 + m][n] = __builtin_amdgcn_mfma_f32_16x16x32_bf16(      \
              AFR[m], bfr[KC][n], acc[(MH)*MH2 + m][n], 0, 0, 0);              \
  __builtin_amdgcn_s_setprio(0);
#define BAR1()                                                                 \
  __builtin_amdgcn_s_barrier();                                                \
  asm volatile("s_waitcnt lgkmcnt(0)" ::: "memory");                           \
  __builtin_amdgcn_sched_barrier(0);
#define BAR2() __builtin_amdgcn_s_barrier();

    // prologue: tile0 fully + tile1 minus Ak1 (completed by first P1)
    stageB(0, 0); stageA(0, 0); stageB(0, 1); stageA(0, 1);
    stageB(1, 0); stageA(1, 0); stageB(1, 1);
    waitcnt_vm<VM_LEAVE>();
    __builtin_amdgcn_s_barrier();

    for (int i = 0; i < NI - 1; i++) {
      const int ta = 2 * i, tb = 2 * i + 1;
      LDB(0, 0); LDA(0, 0, 0, afrA); stageA(tb, 1);     BAR1(); MFMAS(0, 0, afrA); BAR2();
      LDA(0, 0, 1, afrB);            stageB(ta + 2, 0); BAR1(); MFMAS(0, 1, afrB); BAR2();
      LDB(0, 1); LDA(0, 1, 0, afrA); stageA(ta + 2, 0); BAR1(); MFMAS(1, 0, afrA); BAR2();
      LDA(0, 1, 1, afrB);            stageB(ta + 2, 1);
      waitcnt_vm<VM_LEAVE>();                           BAR1(); MFMAS(1, 1, afrB); BAR2();
      LDB(1, 0); LDA(1, 0, 0, afrA); stageA(ta + 2, 1); BAR1(); MFMAS(0, 0, afrA); BAR2();
      LDA(1, 0, 1, afrB);            stageB(tb + 2, 0); BAR1(); MFMAS(0, 1, afrB); BAR2();
      LDB(1, 1); LDA(1, 1, 0, afrA); stageA(tb + 2, 0); BAR1(); MFMAS(1, 0, afrA); BAR2();
      LDA(1, 1, 1, afrB);            stageB(tb + 2, 1);
      waitcnt_vm<VM_LEAVE>();                           BAR1(); MFMAS(1, 1, afrB); BAR2();
    }
    {  // tail: tiles nt-2, nt-1; no further staging
      const int tb = nt - 1;
      LDB(0, 0); LDA(0, 0, 0, afrA); stageA(tb, 1); BAR1(); MFMAS(0, 0, afrA); BAR2();
      LDA(0, 0, 1, afrB);                           BAR1(); MFMAS(0, 1, afrB); BAR2();
      LDB(0, 1); LDA(0, 1, 0, afrA);                BAR1(); MFMAS(1, 0, afrA); BAR2();
      LDA(0, 1, 1, afrB); waitcnt_vm<0>();          BAR1(); MFMAS(1, 1, afrB); BAR2();
      LDB(1, 0); LDA(1, 0, 0, afrA);                BAR1(); MFMAS(0, 0, afrA); BAR2();
      LDA(1, 0, 1, afrB);                           BAR1(); MFMAS(0, 1, afrB); BAR2();
      LDB(1, 1); LDA(1, 1, 0, afrA);                BAR1(); MFMAS(1, 0, afrA); BAR2();
      LDA(1, 1, 1, afrB);                           BAR1(); MFMAS(1, 1, afrB); BAR2();
    }
#undef LDB
#undef LDA
#undef MFMAS
#undef BAR1
#undef BAR2

    // epilogue: D row = (lane>>4)*4 + j, col = lane&15 (m89-verified)
    const int cr0 = tm * BM + wr * (BM / WM) + (lane >> 4) * 4;
    const int cc0 = tn * BN + wc * (BN / WN) + (lane & 15);
#pragma unroll
    for (int m = 0; m < MR; m++)
#pragma unroll
      for (int n = 0; n < NR; n++)
#pragma unroll
        for (int j = 0; j < 4; j++) {
          long row = cr0 + m * 16 + j;
          long col = cc0 + n * 16;
          if (OUT == 1)
            ((bf16*)C)[row * (long)ldc + col] = __float2bfloat16(acc[m][n][j]);
          else if (OUT == 2)
            ((__half*)C)[row * (long)ldc + col] = __float2half(acc[m][n][j]);
          else
            ((float*)C)[row * (long)ldc + col] = acc[m][n][j];
        }
  }
}

// ---------------------------------------------------------------------------
// fused fp32 -> bf16 convert for x, Wq, Wk, Wv (one dispatch)
// ---------------------------------------------------------------------------
__global__ __launch_bounds__(256) void cvt_all(const float* __restrict__ x,
                                               const float* __restrict__ wq,
                                               const float* __restrict__ wk,
                                               const float* __restrict__ wv,
                                               bf16* __restrict__ xb,
                                               bf16* __restrict__ wb) {
  const int b = blockIdx.x;
  const float* src;
  bf16* dst;
  int i;
  if (b < 8192) { src = x; dst = xb; i = b * 256 + threadIdx.x; }
  else if (b < 9216) { src = wq; dst = wb; i = (b - 8192) * 256 + threadIdx.x; }
  else if (b < 10240) { src = wk; dst = wb + 1048576; i = (b - 9216) * 256 + threadIdx.x; }
  else { src = wv; dst = wb + 2097152; i = (b - 10240) * 256 + threadIdx.x; }
  float4 f = ((const float4*)src)[i];
  union { bf16 h[4]; uint2 u; } o;
  o.h[0] = __float2bfloat16(f.x);
  o.h[1] = __float2bfloat16(f.y);
  o.h[2] = __float2bfloat16(f.z);
  o.h[3] = __float2bfloat16(f.w);
  ((uint2*)dst)[i] = o.u;
}

// ---------------------------------------------------------------------------
// causal row softmax on fp16 scores: P = softmax_j<=i(S/32), 0 for j>i (bf16)
// ---------------------------------------------------------------------------
typedef short short4v __attribute__((ext_vector_type(4)));

__global__ __launch_bounds__(256) void softmax_causal(const __half* __restrict__ Sc,
                                                      bf16* __restrict__ P) {
  const int i = blockIdx.x, b = blockIdx.y;
  const long base = ((long)b * 2048 + i) * 2048;
  const __half* row = Sc + base;
  bf16* prow = P + base;
  const int tid = threadIdx.x, lane = tid & 63, wv = tid >> 6;
  const int len = i + 1;

  float v[8];
  float m = -3.3e38f;
  {
    const int j0 = tid * 8;
    union { short4v s[2]; __half h[8]; } u;
    u.s[0] = *(const short4v*)(row + j0);
    u.s[1] = *(const short4v*)(row + j0 + 4);
#pragma unroll
    for (int e = 0; e < 8; e++) {
      float t = __half2float(u.h[e]);
      v[e] = (j0 + e < len) ? t : -3.3e38f;
      m = fmaxf(m, v[e]);
    }
  }
  for (int o = 32; o; o >>= 1) m = fmaxf(m, __shfl_xor(m, o));
  __shared__ float redm[4], reds[4];
  if (lane == 0) redm[wv] = m;
  __syncthreads();
  m = fmaxf(fmaxf(redm[0], redm[1]), fmaxf(redm[2], redm[3]));

  const float scale = 0.03125f;  // 1/sqrt(1024)
  float e8[8];
  float s = 0.f;
  {
    const int j0 = tid * 8;
#pragma unroll
    for (int e = 0; e < 8; e++) {
      float t = (j0 + e < len) ? __expf((v[e] - m) * scale) : 0.f;
      e8[e] = t;
      s += t;
    }
  }
  for (int o = 32; o; o >>= 1) s += __shfl_xor(s, o);
  if (lane == 0) reds[wv] = s;
  __syncthreads();
  s = reds[0] + reds[1] + reds[2] + reds[3];
  const float inv = 1.0f / s;
  {
    const int j0 = tid * 8;
    union { bf16 h[8]; uint4 u4; } o;
#pragma unroll
    for (int e = 0; e < 8; e++) o.h[e] = __float2bfloat16(e8[e] * inv);
    *(uint4*)(prow + j0) = o.u4;
  }
}

// ---------------------------------------------------------------------------
// V (cols 2048.. of Cqkv, row stride 3072) -> Vt[b,d,s] (bf16)
// ---------------------------------------------------------------------------
__global__ __launch_bounds__(256) void transposeV(const bf16* __restrict__ V,
                                                  bf16* __restrict__ Vt) {
  __shared__ bf16 t[32][33];
  const int b = blockIdx.z;
  const int s0 = blockIdx.x << 5;
  const int d0 = blockIdx.y << 5;
  const bf16* Vb = V + (long)b * 2048 * 3072;
  bf16* Vtb = Vt + (long)b * 1024 * 2048;
  const int lx = threadIdx.x & 31, ly = threadIdx.x >> 5;
#pragma unroll
  for (int r = 0; r < 32; r += 8)
    t[r + ly][lx] = Vb[(long)(s0 + r + ly) * 3072 + d0 + lx];
  __syncthreads();
#pragma unroll
  for (int r = 0; r < 32; r += 8)
    Vtb[(long)(d0 + r + ly) * 2048 + s0 + lx] = t[lx][r + ly];
}

// ---------------------------------------------------------------------------
// Workspace (160 MB):
//   [0,48M)    Cqkv bf16 [8192][3072]  (Q|K|V interleaved, ld=3072)
//   [48,64M)   Vt bf16 [4][1024][2048]
//   [64,96M)   P bf16 [4][2048][2048]
//   [96,128M)  Sc fp16 [4][2048][2048] -- aliases xb@96M + Wb@112M (dead
//                                         after QKV GEMM; Sc written later)
// ---------------------------------------------------------------------------
extern "C" void kernel_launch(void* const* d_in, const int* in_sizes, int n_in,
                              void* d_out, int out_size, void* d_ws, size_t ws_size,
                              hipStream_t stream) {
  const float* x = (const float*)d_in[0];
  const float* Wq = (const float*)d_in[1];
  const float* Wk = (const float*)d_in[2];
  const float* Wv = (const float*)d_in[3];

  const long MBy = 1 << 20;
  char* ws = (char*)d_ws;
  bf16* Cqkv = (bf16*)(ws);
  bf16* Vt = (bf16*)(ws + 48 * MBy);
  bf16* P = (bf16*)(ws + 64 * MBy);
  __half* Sc = (__half*)(ws + 96 * MBy);
  bf16* xb = (bf16*)(ws + 96 * MBy);
  bf16* Wb = (bf16*)(ws + 112 * MBy);

  // 1) convert inputs to bf16 (single dispatch)
  cvt_all<<<11264, 256, 0, stream>>>(x, Wq, Wk, Wv, xb, Wb);

  // 2) fused QKV: [8192,3072] = xb * Wb^T. R4 config (best measured): BM=128,
  //    BN=256, 8 waves (2x4, wave 64x64), 768 blocks = 3 exact rounds.
  gemmT<128, 256, 2, 4, 512, 2, 1, false, false, 1><<<dim3(12, 64), 512, 0, stream>>>(
      xb, Wb, Cqkv, 1024, 1024, 1024, 3072, 0L, 0L, 0L);

  // 3) V transpose (V = Cqkv cols [2048,3072), row stride 3072)
  transposeV<<<dim3(64, 32, 4), 256, 0, stream>>>(Cqkv + 2048, Vt);

  // 4) scores: per batch S = Q*K^T (fp16 out), skip masked tiles.
  //    BM=BN=128, 4 waves (2x2), 64KB LDS -> 2 blocks/CU, 544 live blocks.
  gemmT<128, 128, 2, 2, 256, 2, 2, true, false, 1><<<dim3(16, 16, 4), 256, 0, stream>>>(
      Cqkv, Cqkv + 1024, Sc, 1024, 3072, 3072, 2048,
      2048L * 3072, 2048L * 3072, 2048L * 2048 * 2);

  // 5) causal softmax (applies 1/32 scale), P bf16 with zeros above diagonal
  softmax_causal<<<dim3(2048, 4), 256, 0, stream>>>(Sc, P);

  // 6) out = P * Vt^T fp32, causal K-limit, PAIRED row-tiles (y, 15-y):
  //    constant K-work 2176 per block, 256 balanced blocks @ 2/CU.
  gemmT<128, 128, 2, 2, 256, 2, 0, false, true, 2><<<dim3(8, 8, 4), 256, 0, stream>>>(
      P, Vt, d_out, 2048, 2048, 2048, 1024,
      2048L * 2048, 1024L * 2048, 2048L * 1024 * 4);
}

// Round 7
// 163.268 us; speedup vs baseline: 1.1593x; 1.0521x over previous
//
#include <hip/hip_runtime.h>
#include <hip/hip_bf16.h>
#include <hip/hip_fp16.h>

// CausalSelfAttention  B=4, S=2048, D=1024 (single wide head), fp32 in/out.
// R7: single change vs R6 — QKV GEMM moved to 2-blocks/CU config
// (BM=BN=128, 4 waves, 64KB LDS, OCC=2, grid 24x64=1536 blocks) to hide the
// block-wide barrier drains via co-resident-block overlap.

using bf16 = __hip_bfloat16;
typedef __bf16 bf16x8 __attribute__((ext_vector_type(8)));
typedef float f32x4 __attribute__((ext_vector_type(4)));

__device__ __forceinline__ void load_lds_16B(const void* g, void* l) {
  __builtin_amdgcn_global_load_lds(
      (const __attribute__((address_space(1))) unsigned int*)g,
      (__attribute__((address_space(3))) unsigned int*)l, 16, 0, 0);
}

template <int N>
__device__ __forceinline__ void waitcnt_vm() {
  if constexpr (N == 8) asm volatile("s_waitcnt vmcnt(8)" ::: "memory");
  else if constexpr (N == 6) asm volatile("s_waitcnt vmcnt(6)" ::: "memory");
  else if constexpr (N == 5) asm volatile("s_waitcnt vmcnt(5)" ::: "memory");
  else asm volatile("s_waitcnt vmcnt(0)" ::: "memory");
}

// XOR bits[6:4] by bits[9:7] (disjoint -> involution). Verified 0 bank
// conflicts (R2-R6 rocprof).
__device__ __forceinline__ int swz(int o) { return o ^ (((o >> 7) & 7) << 4); }

// ---------------------------------------------------------------------------
// NT GEMM: C[M,N] = A[M,K]*B[N,K]^T, strides lda/ldb/ldc (elements).
// WM x WN waves, wave tile (BM/WM) x (BN/WN). BK=64 as two kc=32 chunks.
// 8 phases / 2 K-tiles; 1 staging half-chunk per phase; counted vmcnt at
// phases 4 & 8. OUT: 0=fp32, 1=bf16, 2=fp16.
// NPASS=2: block serially processes row-tiles blockIdx.y and
// 2*gridDim.y-1-blockIdx.y (KLIM pairing -> constant total K per block).
// ---------------------------------------------------------------------------
template <int BM, int BN, int WM, int WN, int STHR, int OCC, int OUT,
          bool CSKIP, bool KLIM, int NPASS>
__global__ __launch_bounds__(WM* WN * 64, OCC) void gemmT(
    const bf16* __restrict__ A, const bf16* __restrict__ Bm, void* __restrict__ Cv,
    int K, int lda, int ldb, int ldc, long sAz, long sBz, long sCzBytes) {
  constexpr int MR = BM / WM / 16, NR = BN / WN / 16, MH2 = MR / 2;
  constexpr int AKC = BM * 64;   // bytes per A kc-chunk [BM][32]bf16
  constexpr int BKC = BN * 64;   // bytes per B kc-chunk
  constexpr int DBSTR = 2 * (AKC + BKC);
  constexpr int CHUNK = STHR * 16;
  constexpr int ACALLS = AKC / CHUNK;
  constexpr int BCALLS = BKC / CHUNK;
  constexpr int VM_LEAVE = ACALLS + 2 * BCALLS;

  const int tn = blockIdx.x, z = blockIdx.z;
  if (CSKIP && (long)tn * BN >= (long)blockIdx.y * BM + BM) return;
  A += (long)z * sAz;
  Bm += (long)z * sBz;
  char* C = (char*)Cv + (long)z * sCzBytes;

  __shared__ __align__(128) char sm[2 * DBSTR];
  const int tid = threadIdx.x, lane = tid & 63, wv = tid >> 6;
  const int wr = wv / WN, wc = wv % WN;
  const int ldsw = wv * 1024;
  const int ts = (tid < STHR) ? tid : 0;

  int aoff[MR], boff[NR];
#pragma unroll
  for (int m = 0; m < MR; m++)
    aoff[m] = swz((wr * (BM / WM) + m * 16 + (lane & 15)) * 64 + (lane >> 4) * 16);
#pragma unroll
  for (int n = 0; n < NR; n++)
    boff[n] = 2 * AKC + swz((wc * (BN / WN) + n * 16 + (lane & 15)) * 64 + (lane >> 4) * 16);

  const char* srcB[BCALLS];
#pragma unroll
  for (int c = 0; c < BCALLS; c++) {
    int os = swz(c * CHUNK + ts * 16);
    srcB[c] = (const char*)(Bm + ((long)tn * BN + (os >> 6)) * ldb) + (os & 63);
  }

  for (int pass = 0; pass < NPASS; ++pass) {
    const int tm = (NPASS == 2)
                       ? (pass == 0 ? blockIdx.y : 2 * (int)gridDim.y - 1 - (int)blockIdx.y)
                       : (int)blockIdx.y;

    int kEnd = K;
    if (KLIM) kEnd = min(tm * BM + BM, K);  // causal PV: P[q,k]==0 for k>q
    int nt = kEnd >> 6;
    if (KLIM) nt = (nt + 1) & ~1;  // even tiles; extra K reads zeros of P
    const int NI = nt >> 1;

    const char* srcA[ACALLS];
#pragma unroll
    for (int c = 0; c < ACALLS; c++) {
      int os = swz(c * CHUNK + ts * 16);
      srcA[c] = (const char*)(A + ((long)tm * BM + (os >> 6)) * lda) + (os & 63);
    }
    auto stageA = [&](int t, int kc) {
      if (tid < STHR) {
#pragma unroll
        for (int c = 0; c < ACALLS; c++)
          load_lds_16B(srcA[c] + (long)t * 128 + kc * 64,
                       sm + (t & 1) * DBSTR + kc * AKC + c * CHUNK + ldsw);
      }
    };
    auto stageB = [&](int t, int kc) {
      if (tid < STHR) {
#pragma unroll
        for (int c = 0; c < BCALLS; c++)
          load_lds_16B(srcB[c] + (long)t * 128 + kc * 64,
                       sm + (t & 1) * DBSTR + 2 * AKC + kc * BKC + c * CHUNK + ldsw);
      }
    };

    f32x4 acc[MR][NR] = {};
    bf16x8 bfr[2][NR];
    bf16x8 afrA[MH2], afrB[MH2];

#define LDB(DBUF, KC)                                                          \
  _Pragma("unroll") for (int n = 0; n < NR; n++)                               \
      bfr[KC][n] = *(const bf16x8*)(sm + (DBUF)*DBSTR + (KC)*BKC + boff[n]);
#define LDA(DBUF, KC, MH, DST)                                                 \
  _Pragma("unroll") for (int m = 0; m < MH2; m++)                              \
      DST[m] = *(const bf16x8*)(sm + (DBUF)*DBSTR + (KC)*AKC + aoff[(MH)*MH2 + m]);
#define MFMAS(KC, MH, AFR)                                                     \
  __builtin_amdgcn_s_setprio(1);                                               \
  _Pragma("unroll") for (int m = 0; m < MH2; m++)                              \
      _Pragma("unroll") for (int n = 0; n < NR; n++)                           \
          acc[(MH)*MH2 + m][n] = __builtin_amdgcn_mfma_f32_16x16x32_bf16(      \
              AFR[m], bfr[KC][n], acc[(MH)*MH2 + m][n], 0, 0, 0);              \
  __builtin_amdgcn_s_setprio(0);
#define BAR1()                                                                 \
  __builtin_amdgcn_s_barrier();                                                \
  asm volatile("s_waitcnt lgkmcnt(0)" ::: "memory");                           \
  __builtin_amdgcn_sched_barrier(0);
#define BAR2() __builtin_amdgcn_s_barrier();

    // prologue: tile0 fully + tile1 minus Ak1 (completed by first P1)
    stageB(0, 0); stageA(0, 0); stageB(0, 1); stageA(0, 1);
    stageB(1, 0); stageA(1, 0); stageB(1, 1);
    waitcnt_vm<VM_LEAVE>();
    __builtin_amdgcn_s_barrier();

    for (int i = 0; i < NI - 1; i++) {
      const int ta = 2 * i, tb = 2 * i + 1;
      LDB(0, 0); LDA(0, 0, 0, afrA); stageA(tb, 1);     BAR1(); MFMAS(0, 0, afrA); BAR2();
      LDA(0, 0, 1, afrB);            stageB(ta + 2, 0); BAR1(); MFMAS(0, 1, afrB); BAR2();
      LDB(0, 1); LDA(0, 1, 0, afrA); stageA(ta + 2, 0); BAR1(); MFMAS(1, 0, afrA); BAR2();
      LDA(0, 1, 1, afrB);            stageB(ta + 2, 1);
      waitcnt_vm<VM_LEAVE>();                           BAR1(); MFMAS(1, 1, afrB); BAR2();
      LDB(1, 0); LDA(1, 0, 0, afrA); stageA(ta + 2, 1); BAR1(); MFMAS(0, 0, afrA); BAR2();
      LDA(1, 0, 1, afrB);            stageB(tb + 2, 0); BAR1(); MFMAS(0, 1, afrB); BAR2();
      LDB(1, 1); LDA(1, 1, 0, afrA); stageA(tb + 2, 0); BAR1(); MFMAS(1, 0, afrA); BAR2();
      LDA(1, 1, 1, afrB);            stageB(tb + 2, 1);
      waitcnt_vm<VM_LEAVE>();                           BAR1(); MFMAS(1, 1, afrB); BAR2();
    }
    {  // tail: tiles nt-2, nt-1; no further staging
      const int tb = nt - 1;
      LDB(0, 0); LDA(0, 0, 0, afrA); stageA(tb, 1); BAR1(); MFMAS(0, 0, afrA); BAR2();
      LDA(0, 0, 1, afrB);                           BAR1(); MFMAS(0, 1, afrB); BAR2();
      LDB(0, 1); LDA(0, 1, 0, afrA);                BAR1(); MFMAS(1, 0, afrA); BAR2();
      LDA(0, 1, 1, afrB); waitcnt_vm<0>();          BAR1(); MFMAS(1, 1, afrB); BAR2();
      LDB(1, 0); LDA(1, 0, 0, afrA);                BAR1(); MFMAS(0, 0, afrA); BAR2();
      LDA(1, 0, 1, afrB);                           BAR1(); MFMAS(0, 1, afrB); BAR2();
      LDB(1, 1); LDA(1, 1, 0, afrA);                BAR1(); MFMAS(1, 0, afrA); BAR2();
      LDA(1, 1, 1, afrB);                           BAR1(); MFMAS(1, 1, afrB); BAR2();
    }
#undef LDB
#undef LDA
#undef MFMAS
#undef BAR1
#undef BAR2

    // epilogue: D row = (lane>>4)*4 + j, col = lane&15 (m89-verified)
    const int cr0 = tm * BM + wr * (BM / WM) + (lane >> 4) * 4;
    const int cc0 = tn * BN + wc * (BN / WN) + (lane & 15);
#pragma unroll
    for (int m = 0; m < MR; m++)
#pragma unroll
      for (int n = 0; n < NR; n++)
#pragma unroll
        for (int j = 0; j < 4; j++) {
          long row = cr0 + m * 16 + j;
          long col = cc0 + n * 16;
          if (OUT == 1)
            ((bf16*)C)[row * (long)ldc + col] = __float2bfloat16(acc[m][n][j]);
          else if (OUT == 2)
            ((__half*)C)[row * (long)ldc + col] = __float2half(acc[m][n][j]);
          else
            ((float*)C)[row * (long)ldc + col] = acc[m][n][j];
        }
  }
}

// ---------------------------------------------------------------------------
// fused fp32 -> bf16 convert for x, Wq, Wk, Wv (one dispatch)
// ---------------------------------------------------------------------------
__global__ __launch_bounds__(256) void cvt_all(const float* __restrict__ x,
                                               const float* __restrict__ wq,
                                               const float* __restrict__ wk,
                                               const float* __restrict__ wv,
                                               bf16* __restrict__ xb,
                                               bf16* __restrict__ wb) {
  const int b = blockIdx.x;
  const float* src;
  bf16* dst;
  int i;
  if (b < 8192) { src = x; dst = xb; i = b * 256 + threadIdx.x; }
  else if (b < 9216) { src = wq; dst = wb; i = (b - 8192) * 256 + threadIdx.x; }
  else if (b < 10240) { src = wk; dst = wb + 1048576; i = (b - 9216) * 256 + threadIdx.x; }
  else { src = wv; dst = wb + 2097152; i = (b - 10240) * 256 + threadIdx.x; }
  float4 f = ((const float4*)src)[i];
  union { bf16 h[4]; uint2 u; } o;
  o.h[0] = __float2bfloat16(f.x);
  o.h[1] = __float2bfloat16(f.y);
  o.h[2] = __float2bfloat16(f.z);
  o.h[3] = __float2bfloat16(f.w);
  ((uint2*)dst)[i] = o.u;
}

// ---------------------------------------------------------------------------
// causal row softmax on fp16 scores: P = softmax_j<=i(S/32), 0 for j>i (bf16)
// ---------------------------------------------------------------------------
typedef short short4v __attribute__((ext_vector_type(4)));

__global__ __launch_bounds__(256) void softmax_causal(const __half* __restrict__ Sc,
                                                      bf16* __restrict__ P) {
  const int i = blockIdx.x, b = blockIdx.y;
  const long base = ((long)b * 2048 + i) * 2048;
  const __half* row = Sc + base;
  bf16* prow = P + base;
  const int tid = threadIdx.x, lane = tid & 63, wv = tid >> 6;
  const int len = i + 1;

  float v[8];
  float m = -3.3e38f;
  {
    const int j0 = tid * 8;
    union { short4v s[2]; __half h[8]; } u;
    u.s[0] = *(const short4v*)(row + j0);
    u.s[1] = *(const short4v*)(row + j0 + 4);
#pragma unroll
    for (int e = 0; e < 8; e++) {
      float t = __half2float(u.h[e]);
      v[e] = (j0 + e < len) ? t : -3.3e38f;
      m = fmaxf(m, v[e]);
    }
  }
  for (int o = 32; o; o >>= 1) m = fmaxf(m, __shfl_xor(m, o));
  __shared__ float redm[4], reds[4];
  if (lane == 0) redm[wv] = m;
  __syncthreads();
  m = fmaxf(fmaxf(redm[0], redm[1]), fmaxf(redm[2], redm[3]));

  const float scale = 0.03125f;  // 1/sqrt(1024)
  float e8[8];
  float s = 0.f;
  {
    const int j0 = tid * 8;
#pragma unroll
    for (int e = 0; e < 8; e++) {
      float t = (j0 + e < len) ? __expf((v[e] - m) * scale) : 0.f;
      e8[e] = t;
      s += t;
    }
  }
  for (int o = 32; o; o >>= 1) s += __shfl_xor(s, o);
  if (lane == 0) reds[wv] = s;
  __syncthreads();
  s = reds[0] + reds[1] + reds[2] + reds[3];
  const float inv = 1.0f / s;
  {
    const int j0 = tid * 8;
    union { bf16 h[8]; uint4 u4; } o;
#pragma unroll
    for (int e = 0; e < 8; e++) o.h[e] = __float2bfloat16(e8[e] * inv);
    *(uint4*)(prow + j0) = o.u4;
  }
}

// ---------------------------------------------------------------------------
// V (cols 2048.. of Cqkv, row stride 3072) -> Vt[b,d,s] (bf16)
// ---------------------------------------------------------------------------
__global__ __launch_bounds__(256) void transposeV(const bf16* __restrict__ V,
                                                  bf16* __restrict__ Vt) {
  __shared__ bf16 t[32][33];
  const int b = blockIdx.z;
  const int s0 = blockIdx.x << 5;
  const int d0 = blockIdx.y << 5;
  const bf16* Vb = V + (long)b * 2048 * 3072;
  bf16* Vtb = Vt + (long)b * 1024 * 2048;
  const int lx = threadIdx.x & 31, ly = threadIdx.x >> 5;
#pragma unroll
  for (int r = 0; r < 32; r += 8)
    t[r + ly][lx] = Vb[(long)(s0 + r + ly) * 3072 + d0 + lx];
  __syncthreads();
#pragma unroll
  for (int r = 0; r < 32; r += 8)
    Vtb[(long)(d0 + r + ly) * 2048 + s0 + lx] = t[lx][r + ly];
}

// ---------------------------------------------------------------------------
// Workspace (160 MB):
//   [0,48M)    Cqkv bf16 [8192][3072]  (Q|K|V interleaved, ld=3072)
//   [48,64M)   Vt bf16 [4][1024][2048]
//   [64,96M)   P bf16 [4][2048][2048]
//   [96,128M)  Sc fp16 [4][2048][2048] -- aliases xb@96M + Wb@112M (dead
//                                         after QKV GEMM; Sc written later)
// ---------------------------------------------------------------------------
extern "C" void kernel_launch(void* const* d_in, const int* in_sizes, int n_in,
                              void* d_out, int out_size, void* d_ws, size_t ws_size,
                              hipStream_t stream) {
  const float* x = (const float*)d_in[0];
  const float* Wq = (const float*)d_in[1];
  const float* Wk = (const float*)d_in[2];
  const float* Wv = (const float*)d_in[3];

  const long MBy = 1 << 20;
  char* ws = (char*)d_ws;
  bf16* Cqkv = (bf16*)(ws);
  bf16* Vt = (bf16*)(ws + 48 * MBy);
  bf16* P = (bf16*)(ws + 64 * MBy);
  __half* Sc = (__half*)(ws + 96 * MBy);
  bf16* xb = (bf16*)(ws + 96 * MBy);
  bf16* Wb = (bf16*)(ws + 112 * MBy);

  // 1) convert inputs to bf16 (single dispatch)
  cvt_all<<<11264, 256, 0, stream>>>(x, Wq, Wk, Wv, xb, Wb);

  // 2) fused QKV: [8192,3072] = xb * Wb^T. R7 single change: BM=BN=128,
  //    4 waves (2x2), 64KB LDS, OCC=2 -> 2 blocks/CU; 1536 blocks = 3 rounds
  //    of co-resident pairs (barrier drains hidden by the sibling block).
  gemmT<128, 128, 2, 2, 256, 2, 1, false, false, 1><<<dim3(24, 64), 256, 0, stream>>>(
      xb, Wb, Cqkv, 1024, 1024, 1024, 3072, 0L, 0L, 0L);

  // 3) V transpose (V = Cqkv cols [2048,3072), row stride 3072)
  transposeV<<<dim3(64, 32, 4), 256, 0, stream>>>(Cqkv + 2048, Vt);

  // 4) scores: per batch S = Q*K^T (fp16 out), skip masked tiles.
  //    BM=BN=128, 4 waves (2x2), 64KB LDS -> 2 blocks/CU, 544 live blocks.
  gemmT<128, 128, 2, 2, 256, 2, 2, true, false, 1><<<dim3(16, 16, 4), 256, 0, stream>>>(
      Cqkv, Cqkv + 1024, Sc, 1024, 3072, 3072, 2048,
      2048L * 3072, 2048L * 3072, 2048L * 2048 * 2);

  // 5) causal softmax (applies 1/32 scale), P bf16 with zeros above diagonal
  softmax_causal<<<dim3(2048, 4), 256, 0, stream>>>(Sc, P);

  // 6) out = P * Vt^T fp32, causal K-limit, PAIRED row-tiles (y, 15-y):
  //    constant K-work 2176 per block, 256 balanced blocks @ 2/CU.
  gemmT<128, 128, 2, 2, 256, 2, 0, false, true, 2><<<dim3(8, 8, 4), 256, 0, stream>>>(
      P, Vt, d_out, 2048, 2048, 2048, 1024,
      2048L * 2048, 1024L * 2048, 2048L * 1024 * 4);
}